// Round 4
// baseline (504.141 us; speedup 1.0000x reference)
//
#include <hip/hip_runtime.h>

// DIAGNOSTIC ROUND (R4): R3 structure, but rewrite the full output `reps`=4
// times in one dispatch. Purpose: (1) make our dispatch long enough (~700+ us)
// to appear in the top-5 rocprof table and expose OUR kernel's counters;
// (2) measure steady-state write BW without short-dispatch ramp/launch
// confounds. Output is still fully correct and deterministic every call.
//
//   out[h, i, j] = (j > i) ? -slopes[h] * (j - i) : 0.0f
// H=16, S=4096, float32 [16,4096,4096] = 1.074 GB per pass.

#define ALIBI_S 4096
#define ALIBI_H 16
#define UNROLL  16
#define BLOCK   256

typedef float f32x4 __attribute__((ext_vector_type(4)));

__global__ __launch_bounds__(BLOCK) void alibi_bias_kernel(
    const float* __restrict__ slopes,
    f32x4* __restrict__ out,
    int reps)  // runtime arg so the compiler can't fold the passes
{
    const int h = blockIdx.y;
    const float ns = -slopes[h];  // wave-uniform scalar load, once

    const unsigned int base_f4 = blockIdx.x * (BLOCK * UNROLL) + threadIdx.x;
    f32x4* plane = out + ((size_t)h << 22);  // S*S/4 = 2^22 float4s per plane

    for (int r = 0; r < reps; ++r) {
#pragma unroll
        for (int k = 0; k < UNROLL; ++k) {
            const unsigned int f = base_f4 + (unsigned int)k * BLOCK;  // stride 4 KB
            const unsigned int e = f << 2;
            const int i = (int)(e >> 12);      // row
            const int j = (int)(e & 4095u);    // first of 4 cols

            f32x4 v;
            v.x = (j + 0 > i) ? ns * (float)(j + 0 - i) : 0.0f;
            v.y = (j + 1 > i) ? ns * (float)(j + 1 - i) : 0.0f;
            v.z = (j + 2 > i) ? ns * (float)(j + 2 - i) : 0.0f;
            v.w = (j + 3 > i) ? ns * (float)(j + 3 - i) : 0.0f;

            plane[f] = v;
        }
        // Prevent dead-store elimination across passes (same addr, same value).
        asm volatile("" ::: "memory");
    }
}

extern "C" void kernel_launch(void* const* d_in, const int* in_sizes, int n_in,
                              void* d_out, int out_size, void* d_ws, size_t ws_size,
                              hipStream_t stream) {
    const float* slopes = (const float*)d_in[0];
    f32x4* out = (f32x4*)d_out;

    dim3 grid(ALIBI_S * ALIBI_S / 4 / (BLOCK * UNROLL), ALIBI_H);
    alibi_bias_kernel<<<grid, BLOCK, 0, stream>>>(slopes, out, 4);
}